// Round 1
// baseline (1494.311 us; speedup 1.0000x reference)
//
#include <hip/hip_runtime.h>

// GPT-J attention, B=2 S=2048 HIDDEN=4096 H=16 D=256 ROTARY=64.
// Pipeline: cvt(hs)->bf16 | W^T->bf16 | QKV GEMM (mfma 16x16x32 bf16, q*1/16)
//           | RoPE(Q,K) | V^T | flash attn (online softmax) | out proj -> f32.
// Workspace: 8 x 32MB bf16 slots = 256MB.
//   slot0: hs_bf16 / attn_out (aliased)   slot1: WqT / Vt (aliased)
//   slot2: WkT  slot3: WvT  slot4: WoT    slot5: Q  slot6: K  slot7: V

typedef unsigned short u16;
typedef __attribute__((ext_vector_type(4))) float f32x4;
typedef __attribute__((ext_vector_type(8))) short s16x8;
typedef __attribute__((ext_vector_type(4))) unsigned short u16x4;

#define HID 4096
#define SEQ 2048
#define NMAT (4096ull * 4096ull)

__device__ __forceinline__ u16 f2bf(float x) {
  unsigned int u = __builtin_bit_cast(unsigned int, x);
  u += 0x7FFFu + ((u >> 16) & 1u);   // RNE
  return (u16)(u >> 16);
}
__device__ __forceinline__ float bf2f(u16 x) {
  unsigned int u = ((unsigned int)x) << 16;
  return __builtin_bit_cast(float, u);
}
// async global->LDS, 16B/lane. LDS dest is wave-uniform base + lane*16.
__device__ __forceinline__ void cp16(const void* g, void* l) {
  __builtin_amdgcn_global_load_lds((__attribute__((address_space(1))) void*)(g),
                                   (__attribute__((address_space(3))) void*)(l),
                                   16, 0, 0);
}

// ---------------- fp32 -> bf16 convert (contiguous) ----------------
__global__ __launch_bounds__(256) void k_cvt(const float* __restrict__ src,
                                             u16* __restrict__ dst) {
  size_t i = ((size_t)blockIdx.x * 256 + threadIdx.x) * 8;
  f32x4 a = *(const f32x4*)(src + i);
  f32x4 b = *(const f32x4*)(src + i + 4);
  u16x4 o0, o1;
  o0[0] = f2bf(a[0]); o0[1] = f2bf(a[1]); o0[2] = f2bf(a[2]); o0[3] = f2bf(a[3]);
  o1[0] = f2bf(b[0]); o1[1] = f2bf(b[1]); o1[2] = f2bf(b[2]); o1[3] = f2bf(b[3]);
  *(u16x4*)(dst + i) = o0;
  *(u16x4*)(dst + i + 4) = o1;
}

// ---------------- W [K,N] fp32 -> WT [N,K] bf16 ----------------
__global__ __launch_bounds__(256) void k_wtrans(const float* __restrict__ W0,
                                                const float* __restrict__ W1,
                                                const float* __restrict__ W2,
                                                const float* __restrict__ W3,
                                                u16* __restrict__ WT) {
  int z = blockIdx.z;
  const float* W = (z == 0) ? W0 : (z == 1) ? W1 : (z == 2) ? W2 : W3;
  u16* T = WT + (size_t)z * NMAT;
  __shared__ u16 tile[64][70];   // stride 70: 2-way max on both phases
  int t = threadIdx.x, tx = t & 15, ty = t >> 4;
  int n0 = blockIdx.x * 64, k0 = blockIdx.y * 64;
  for (int i = 0; i < 4; i++) {
    int kl = ty + 16 * i;
    f32x4 v = *(const f32x4*)(W + (size_t)(k0 + kl) * HID + n0 + tx * 4);
    tile[kl][tx * 4 + 0] = f2bf(v[0]);
    tile[kl][tx * 4 + 1] = f2bf(v[1]);
    tile[kl][tx * 4 + 2] = f2bf(v[2]);
    tile[kl][tx * 4 + 3] = f2bf(v[3]);
  }
  __syncthreads();
  for (int i = 0; i < 4; i++) {
    int nl = ty + 16 * i;
    u16x4 o;
    o[0] = tile[tx * 4 + 0][nl];
    o[1] = tile[tx * 4 + 1][nl];
    o[2] = tile[tx * 4 + 2][nl];
    o[3] = tile[tx * 4 + 3][nl];
    *(u16x4*)(T + (size_t)(n0 + nl) * HID + k0 + tx * 4) = o;
  }
}

// ---------------- V [tok][h*256+d] -> Vt [b][h][d][tok] (bf16) ----------------
__global__ __launch_bounds__(256) void k_vtrans(const u16* __restrict__ V,
                                                u16* __restrict__ Vt) {
  int bh = blockIdx.z, b = bh >> 4, h = bh & 15;
  int tok0 = blockIdx.x * 64, d0 = blockIdx.y * 64;
  __shared__ u16 tile[64][70];
  int t = threadIdx.x, tx = t & 15, ty = t >> 4;
  for (int i = 0; i < 4; i++) {
    int tl = ty + 16 * i;
    u16x4 v = *(const u16x4*)(V + (size_t)(b * SEQ + tok0 + tl) * HID + h * 256 + d0 + tx * 4);
    tile[tl][tx * 4 + 0] = v[0];
    tile[tl][tx * 4 + 1] = v[1];
    tile[tl][tx * 4 + 2] = v[2];
    tile[tl][tx * 4 + 3] = v[3];
  }
  __syncthreads();
  for (int i = 0; i < 4; i++) {
    int dl = ty + 16 * i;
    u16x4 o;
    o[0] = tile[tx * 4 + 0][dl];
    o[1] = tile[tx * 4 + 1][dl];
    o[2] = tile[tx * 4 + 2][dl];
    o[3] = tile[tx * 4 + 3][dl];
    *(u16x4*)(Vt + ((size_t)bh * 256 + d0 + dl) * SEQ + tok0 + tx * 4) = o;
  }
}

// ---------------- GEMM C[M,N] = A[M,K] * Bt[N,K]^T (m97 structure) ----------------
// 128x128 tile / 256 thr / BK=32 / global_load_lds x16B / XOR chunk swizzle.
template <bool QKV>
__global__ __launch_bounds__(256) void k_gemm(const u16* __restrict__ A,
                                              const u16* __restrict__ Bt0,
                                              u16* __restrict__ Cb0,
                                              float* __restrict__ Cf) {
  const int t = threadIdx.x, lane = t & 63, w = t >> 6;
  const int bm = blockIdx.y * 128, bn = blockIdx.x * 128;
  const u16* Bt = Bt0;
  u16* Cb = Cb0;
  float scale = 1.f;
  if (QKV) {
    int z = blockIdx.z;
    Bt += (size_t)z * NMAT;
    Cb += (size_t)z * NMAT;
    if (z == 0) scale = 0.0625f;   // q / sqrt(256), commutes with RoPE
  }
  __shared__ u16 As[4096];   // 128 rows x 32 (chunk-swizzled)
  __shared__ u16 Bs[4096];
  // staging: chunk fc = t (call1) / 256+t (call2); row=fc>>2, swizzled col
  int r = t >> 2, cs0 = t & 3, cg = cs0 ^ ((r >> 1) & 3);
  const u16* ga = A + (size_t)(bm + r) * HID + cg * 8;
  const u16* gb = Bt + (size_t)(bn + r) * HID + cg * 8;
  u16* la = As + w * 512;
  u16* lb = Bs + w * 512;
  // loop-invariant fragment pointers (conflict-free after swizzle)
  const int wm = (w >> 1) * 64, wn = (w & 1) * 64;
  const u16* ra[4];
  const u16* rb[4];
  for (int mi = 0; mi < 4; mi++) {
    int row = wm + mi * 16 + (lane & 15);
    int cs = (lane >> 4) ^ ((row >> 1) & 3);
    ra[mi] = As + row * 32 + cs * 8;
  }
  for (int ni = 0; ni < 4; ni++) {
    int row = wn + ni * 16 + (lane & 15);
    int cs = (lane >> 4) ^ ((row >> 1) & 3);
    rb[ni] = Bs + row * 32 + cs * 8;
  }
  f32x4 acc[4][4] = {};
  for (int k0 = 0; k0 < HID; k0 += 32) {
    __syncthreads();
    cp16(ga, la);
    cp16(ga + 64 * HID, la + 2048);
    cp16(gb, lb);
    cp16(gb + 64 * HID, lb + 2048);
    ga += 32;
    gb += 32;
    __syncthreads();
    s16x8 af[4], bf[4];
    for (int mi = 0; mi < 4; mi++) af[mi] = *(const s16x8*)ra[mi];
    for (int ni = 0; ni < 4; ni++) bf[ni] = *(const s16x8*)rb[ni];
    for (int mi = 0; mi < 4; mi++)
      for (int ni = 0; ni < 4; ni++)
        acc[mi][ni] = __builtin_amdgcn_mfma_f32_16x16x32_bf16(af[mi], bf[ni], acc[mi][ni], 0, 0, 0);
  }
  // epilogue: C row=(lane>>4)*4+reg, col=lane&15 (m89-verified)
  for (int mi = 0; mi < 4; mi++)
    for (int ni = 0; ni < 4; ni++) {
      int ml = bm + wm + mi * 16 + ((lane >> 4) << 2);
      int nl = bn + wn + ni * 16 + (lane & 15);
      for (int rr = 0; rr < 4; rr++) {
        float v = acc[mi][ni][rr];
        if (QKV)
          Cb[(size_t)(ml + rr) * HID + nl] = f2bf(v * scale);
        else
          Cf[(size_t)(ml + rr) * HID + nl] = v;
      }
    }
}

// ---------------- interleaved RoPE on first 64 chans of each head ----------------
__global__ __launch_bounds__(256) void k_rope(u16* __restrict__ Q, u16* __restrict__ K,
                                              const int* __restrict__ pid) {
  int i = blockIdx.x * 256 + threadIdx.x;   // token*512 + head*32 + pair
  int m = i >> 9, rem = i & 511, h = rem >> 5, p = rem & 31;
  int pos = pid[m];
  double inv = pow(10000.0, -(double)p / 32.0);
  double ang = (double)pos * inv;
  float sv = (float)sin(ang), cv = (float)cos(ang);
  size_t idx = (size_t)m * HID + h * 256 + 2 * p;
  {
    unsigned int qp = *(const unsigned int*)(Q + idx);
    float a = bf2f((u16)qp), b = bf2f((u16)(qp >> 16));
    unsigned int o = (unsigned int)f2bf(a * cv - b * sv) |
                     ((unsigned int)f2bf(b * cv + a * sv) << 16);
    *(unsigned int*)(Q + idx) = o;
  }
  {
    unsigned int kp = *(const unsigned int*)(K + idx);
    float a = bf2f((u16)kp), b = bf2f((u16)(kp >> 16));
    unsigned int o = (unsigned int)f2bf(a * cv - b * sv) |
                     ((unsigned int)f2bf(b * cv + a * sv) << 16);
    *(unsigned int*)(K + idx) = o;
  }
}

// ---------------- flash attention ----------------
// BQ=128 (4 waves x 32 rows), BK=64, D=256. Q-frags in regs, P via LDS.
__global__ __launch_bounds__(256, 1) void k_flash(const u16* __restrict__ Q,
                                                  const u16* __restrict__ Kg,
                                                  const u16* __restrict__ Vt,
                                                  const float* __restrict__ am,
                                                  u16* __restrict__ O) {
  __shared__ u16 smem[40960];        // 80 KB
  u16* sK = smem;                    // [64 kt][256 d]  swizzled, 32 chunks/row
  u16* sV = smem + 16384;            // [256 d][64 kt]  swizzled, 8 chunks/row
  u16* sP = smem + 32768;            // [128 q][64 kt]  swizzled, 8 chunks/row
  const int t = threadIdx.x, lane = t & 63, w = t >> 6;
  const int qt = gridDim.x - 1 - blockIdx.x;   // longest blocks first
  const int q0 = qt * 128;
  const int bh = blockIdx.y, b = bh >> 4, h = bh & 15;
  const size_t tokb = (size_t)b * SEQ;
  const int ch0 = h * 256;

  // Q tile 128x256 staged once through sK|sV region, then kept in registers
  for (int j = 0; j < 16; j++) {
    int fc = j * 256 + t;
    int r = fc >> 5, cs = fc & 31, cg = cs ^ (r & 7);
    cp16(Q + (tokb + q0 + r) * (size_t)HID + ch0 + cg * 8, smem + j * 2048 + w * 512);
  }
  __syncthreads();
  s16x8 qf[2][8];
  for (int mi = 0; mi < 2; mi++) {
    int rq = w * 32 + mi * 16 + (lane & 15);
    for (int kf = 0; kf < 8; kf++) {
      int cs = ((lane >> 4) + 4 * kf) ^ (rq & 7);
      qf[mi][kf] = *(const s16x8*)(smem + rq * 256 + cs * 8);
    }
  }
  f32x4 oacc[2][16] = {};
  float mrow[2][4], lrow[2][4];
  for (int mi = 0; mi < 2; mi++)
    for (int rr = 0; rr < 4; rr++) { mrow[mi][rr] = -1e30f; lrow[mi][rr] = 0.f; }

  const int ntiles = q0 / 64 + 2;
  for (int it = 0; it < ntiles; it++) {
    const int kt0 = it * 64;
    __syncthreads();   // prev-iter LDS reads done before restage
    for (int j = 0; j < 8; j++) {
      int fc = j * 256 + t;
      int r = fc >> 5, cs = fc & 31, cg = cs ^ (r & 7);
      cp16(Kg + (tokb + kt0 + r) * (size_t)HID + ch0 + cg * 8, sK + j * 2048 + w * 512);
    }
    for (int j = 0; j < 8; j++) {
      int fc = j * 256 + t;
      int rd = fc >> 3, cs = fc & 7, cg = cs ^ (rd & 7);
      cp16(Vt + ((size_t)bh * 256 + rd) * SEQ + kt0 + cg * 8, sV + j * 2048 + w * 512);
    }
    __syncthreads();
    // S = Q K^T  (M=32/wave, N=64, K=256)
    f32x4 sacc[2][4] = {};
    for (int kf = 0; kf < 8; kf++) {
      s16x8 bf[4];
      for (int ni = 0; ni < 4; ni++) {
        int rk = ni * 16 + (lane & 15);
        int cs = ((lane >> 4) + 4 * kf) ^ (rk & 7);
        bf[ni] = *(const s16x8*)(sK + rk * 256 + cs * 8);
      }
      for (int mi = 0; mi < 2; mi++)
        for (int ni = 0; ni < 4; ni++)
          sacc[mi][ni] = __builtin_amdgcn_mfma_f32_16x16x32_bf16(qf[mi][kf], bf[ni], sacc[mi][ni], 0, 0, 0);
    }
    // masks
    float amv[4];
    for (int ni = 0; ni < 4; ni++) amv[ni] = am[b * SEQ + kt0 + ni * 16 + (lane & 15)];
    const bool tail = (kt0 + 64 > q0);   // only diagonal tiles need causal test
    for (int mi = 0; mi < 2; mi++) {
      int rbase = q0 + w * 32 + mi * 16 + ((lane >> 4) << 2);
      for (int ni = 0; ni < 4; ni++) {
        int colg = kt0 + ni * 16 + (lane & 15);
        bool dead = (amv[ni] <= 0.f);
        for (int rr = 0; rr < 4; rr++)
          if (dead || (tail && colg > rbase + rr)) sacc[mi][ni][rr] = -1e30f;
      }
    }
    // online softmax (rows live in 16-lane groups; xor-shuffle 1,2,4,8)
    for (int mi = 0; mi < 2; mi++) {
      float alpha[4];
      for (int rr = 0; rr < 4; rr++) {
        float v = fmaxf(fmaxf(sacc[mi][0][rr], sacc[mi][1][rr]),
                        fmaxf(sacc[mi][2][rr], sacc[mi][3][rr]));
        v = fmaxf(v, __shfl_xor(v, 1));
        v = fmaxf(v, __shfl_xor(v, 2));
        v = fmaxf(v, __shfl_xor(v, 4));
        v = fmaxf(v, __shfl_xor(v, 8));
        float mnew = fmaxf(mrow[mi][rr], v);
        alpha[rr] = __expf(mrow[mi][rr] - mnew);
        mrow[mi][rr] = mnew;
      }
      for (int ni = 0; ni < 4; ni++)
        for (int rr = 0; rr < 4; rr++)
          sacc[mi][ni][rr] = __expf(sacc[mi][ni][rr] - mrow[mi][rr]);
      for (int rr = 0; rr < 4; rr++) {
        float sm = sacc[mi][0][rr] + sacc[mi][1][rr] + sacc[mi][2][rr] + sacc[mi][3][rr];
        sm += __shfl_xor(sm, 1);
        sm += __shfl_xor(sm, 2);
        sm += __shfl_xor(sm, 4);
        sm += __shfl_xor(sm, 8);
        lrow[mi][rr] = lrow[mi][rr] * alpha[rr] + sm;
      }
      for (int nd = 0; nd < 16; nd++)
        for (int rr = 0; rr < 4; rr++) oacc[mi][nd][rr] *= alpha[rr];
      // P -> LDS (C-layout -> A-layout round trip, wave-private rows)
      for (int ni = 0; ni < 4; ni++) {
        int ktl = ni * 16 + (lane & 15);
        for (int rr = 0; rr < 4; rr++) {
          int pq = w * 32 + mi * 16 + ((lane >> 4) << 2) + rr;
          int cs = (ktl >> 3) ^ (pq & 7);
          sP[pq * 64 + cs * 8 + (ktl & 7)] = f2bf(sacc[mi][ni][rr]);
        }
      }
    }
    // O += P V   (N=256, K=64)
    for (int kf2 = 0; kf2 < 2; kf2++) {
      s16x8 pa[2];
      for (int mi = 0; mi < 2; mi++) {
        int pq = w * 32 + mi * 16 + (lane & 15);
        int cs = ((lane >> 4) + 4 * kf2) ^ (pq & 7);
        pa[mi] = *(const s16x8*)(sP + pq * 64 + cs * 8);
      }
      for (int nd = 0; nd < 16; nd++) {
        int rd = nd * 16 + (lane & 15);
        int cs = ((lane >> 4) + 4 * kf2) ^ (rd & 7);
        s16x8 vb = *(const s16x8*)(sV + rd * 64 + cs * 8);
        for (int mi = 0; mi < 2; mi++)
          oacc[mi][nd] = __builtin_amdgcn_mfma_f32_16x16x32_bf16(pa[mi], vb, oacc[mi][nd], 0, 0, 0);
      }
    }
  }
  // epilogue: O / l -> bf16
  for (int mi = 0; mi < 2; mi++) {
    float rl[4];
    for (int rr = 0; rr < 4; rr++) rl[rr] = (lrow[mi][rr] > 0.f) ? 1.f / lrow[mi][rr] : 0.f;
    for (int nd = 0; nd < 16; nd++)
      for (int rr = 0; rr < 4; rr++) {
        size_t row = tokb + q0 + w * 32 + mi * 16 + ((lane >> 4) << 2) + rr;
        O[row * HID + ch0 + nd * 16 + (lane & 15)] = f2bf(oacc[mi][nd][rr] * rl[rr]);
      }
  }
}

extern "C" void kernel_launch(void* const* d_in, const int* in_sizes, int n_in,
                              void* d_out, int out_size, void* d_ws, size_t ws_size,
                              hipStream_t stream) {
  const float* hs = (const float*)d_in[0];
  const float* am = (const float*)d_in[1];
  const int* pid = (const int*)d_in[2];
  const float* Wq = (const float*)d_in[3];
  const float* Wk = (const float*)d_in[4];
  const float* Wv = (const float*)d_in[5];
  const float* Wo = (const float*)d_in[6];
  float* out = (float*)d_out;

  u16* wsp = (u16*)d_ws;
  u16* hsb = wsp;                 // slot 0 (later: attn_out)
  u16* WT = wsp + NMAT;           // slots 1..4: WqT WkT WvT WoT
  u16* Qb = wsp + 5 * NMAT;
  u16* Kb = wsp + 6 * NMAT;
  u16* Vb = wsp + 7 * NMAT;
  u16* Vt = wsp + 1 * NMAT;       // reuse WqT after QKV GEMM
  u16* attn = hsb;                // reuse hs_bf16 after QKV GEMM

  k_cvt<<<8192, 256, 0, stream>>>(hs, hsb);
  k_wtrans<<<dim3(64, 64, 4), 256, 0, stream>>>(Wq, Wk, Wv, Wo, WT);
  k_gemm<true><<<dim3(32, 32, 3), 256, 0, stream>>>(hsb, WT, Qb, nullptr);
  k_rope<<<8192, 256, 0, stream>>>(Qb, Kb, pid);
  k_vtrans<<<dim3(32, 4, 32), 256, 0, stream>>>(Vb, Vt);
  k_flash<<<dim3(16, 32), 256, 0, stream>>>(Qb, Kb, Vt, am, attn);
  k_gemm<false><<<dim3(32, 32, 1), 256, 0, stream>>>(attn, WT + 3 * NMAT, nullptr, out);
}

// Round 3
// 1258.846 us; speedup vs baseline: 1.1870x; 1.1870x over previous
//
#include <hip/hip_runtime.h>

// GPT-J attention, B=2 S=2048 HIDDEN=4096 H=16 D=256 ROTARY=64.
// Pipeline: cvt(hs)->bf16 | W^T->bf16 | QKV GEMM (mfma 16x16x32 bf16, q*1/16)
//           | RoPE(Q,K) | V^T | flash attn (online softmax) | out proj -> f32.
// R2: flash rewritten — 16 q-rows/wave (oacc 64 + qf 32 regs, no spill),
//     BQ=64, grid 32x32=1024 blocks, LDS 72KB (2 blocks/CU), better sP swizzle.
// R3: fix k_vtrans typo (missing '+').

typedef unsigned short u16;
typedef __attribute__((ext_vector_type(4))) float f32x4;
typedef __attribute__((ext_vector_type(8))) short s16x8;
typedef __attribute__((ext_vector_type(4))) unsigned short u16x4;

#define HID 4096
#define SEQ 2048
#define NMAT (4096ull * 4096ull)

__device__ __forceinline__ u16 f2bf(float x) {
  unsigned int u = __builtin_bit_cast(unsigned int, x);
  u += 0x7FFFu + ((u >> 16) & 1u);   // RNE
  return (u16)(u >> 16);
}
__device__ __forceinline__ float bf2f(u16 x) {
  unsigned int u = ((unsigned int)x) << 16;
  return __builtin_bit_cast(float, u);
}
// async global->LDS, 16B/lane. LDS dest is wave-uniform base + lane*16.
__device__ __forceinline__ void cp16(const void* g, void* l) {
  __builtin_amdgcn_global_load_lds((__attribute__((address_space(1))) void*)(g),
                                   (__attribute__((address_space(3))) void*)(l),
                                   16, 0, 0);
}

// ---------------- fp32 -> bf16 convert (contiguous) ----------------
__global__ __launch_bounds__(256) void k_cvt(const float* __restrict__ src,
                                             u16* __restrict__ dst) {
  size_t i = ((size_t)blockIdx.x * 256 + threadIdx.x) * 8;
  f32x4 a = *(const f32x4*)(src + i);
  f32x4 b = *(const f32x4*)(src + i + 4);
  u16x4 o0, o1;
  o0[0] = f2bf(a[0]); o0[1] = f2bf(a[1]); o0[2] = f2bf(a[2]); o0[3] = f2bf(a[3]);
  o1[0] = f2bf(b[0]); o1[1] = f2bf(b[1]); o1[2] = f2bf(b[2]); o1[3] = f2bf(b[3]);
  *(u16x4*)(dst + i) = o0;
  *(u16x4*)(dst + i + 4) = o1;
}

// ---------------- W [K,N] fp32 -> WT [N,K] bf16 ----------------
__global__ __launch_bounds__(256) void k_wtrans(const float* __restrict__ W0,
                                                const float* __restrict__ W1,
                                                const float* __restrict__ W2,
                                                const float* __restrict__ W3,
                                                u16* __restrict__ WT) {
  int z = blockIdx.z;
  const float* W = (z == 0) ? W0 : (z == 1) ? W1 : (z == 2) ? W2 : W3;
  u16* T = WT + (size_t)z * NMAT;
  __shared__ u16 tile[64][70];   // stride 70: 2-way max on both phases
  int t = threadIdx.x, tx = t & 15, ty = t >> 4;
  int n0 = blockIdx.x * 64, k0 = blockIdx.y * 64;
  for (int i = 0; i < 4; i++) {
    int kl = ty + 16 * i;
    f32x4 v = *(const f32x4*)(W + (size_t)(k0 + kl) * HID + n0 + tx * 4);
    tile[kl][tx * 4 + 0] = f2bf(v[0]);
    tile[kl][tx * 4 + 1] = f2bf(v[1]);
    tile[kl][tx * 4 + 2] = f2bf(v[2]);
    tile[kl][tx * 4 + 3] = f2bf(v[3]);
  }
  __syncthreads();
  for (int i = 0; i < 4; i++) {
    int nl = ty + 16 * i;
    u16x4 o;
    o[0] = tile[tx * 4 + 0][nl];
    o[1] = tile[tx * 4 + 1][nl];
    o[2] = tile[tx * 4 + 2][nl];
    o[3] = tile[tx * 4 + 3][nl];
    *(u16x4*)(T + (size_t)(n0 + nl) * HID + k0 + tx * 4) = o;
  }
}

// ---------------- V [tok][h*256+d] -> Vt [b][h][d][tok] (bf16) ----------------
__global__ __launch_bounds__(256) void k_vtrans(const u16* __restrict__ V,
                                                u16* __restrict__ Vt) {
  int bh = blockIdx.z, b = bh >> 4, h = bh & 15;
  int tok0 = blockIdx.x * 64, d0 = blockIdx.y * 64;
  __shared__ u16 tile[64][70];
  int t = threadIdx.x, tx = t & 15, ty = t >> 4;
  for (int i = 0; i < 4; i++) {
    int tl = ty + 16 * i;
    u16x4 v = *(const u16x4*)(V + (size_t)(b * SEQ + tok0 + tl) * HID + h * 256 + d0 + tx * 4);
    tile[tl][tx * 4 + 0] = v[0];
    tile[tl][tx * 4 + 1] = v[1];
    tile[tl][tx * 4 + 2] = v[2];
    tile[tl][tx * 4 + 3] = v[3];
  }
  __syncthreads();
  for (int i = 0; i < 4; i++) {
    int dl = ty + 16 * i;
    u16x4 o;
    o[0] = tile[tx * 4 + 0][dl];
    o[1] = tile[tx * 4 + 1][dl];
    o[2] = tile[tx * 4 + 2][dl];
    o[3] = tile[tx * 4 + 3][dl];
    *(u16x4*)(Vt + ((size_t)bh * 256 + d0 + dl) * SEQ + tok0 + tx * 4) = o;
  }
}

// ---------------- GEMM C[M,N] = A[M,K] * Bt[N,K]^T (m97 structure) ----------------
// 128x128 tile / 256 thr / BK=32 / global_load_lds x16B / XOR chunk swizzle.
template <bool QKV>
__global__ __launch_bounds__(256) void k_gemm(const u16* __restrict__ A,
                                              const u16* __restrict__ Bt0,
                                              u16* __restrict__ Cb0,
                                              float* __restrict__ Cf) {
  const int t = threadIdx.x, lane = t & 63, w = t >> 6;
  const int bm = blockIdx.y * 128, bn = blockIdx.x * 128;
  const u16* Bt = Bt0;
  u16* Cb = Cb0;
  float scale = 1.f;
  if (QKV) {
    int z = blockIdx.z;
    Bt += (size_t)z * NMAT;
    Cb += (size_t)z * NMAT;
    if (z == 0) scale = 0.0625f;   // q / sqrt(256), commutes with RoPE
  }
  __shared__ u16 As[4096];   // 128 rows x 32 (chunk-swizzled)
  __shared__ u16 Bs[4096];
  int r = t >> 2, cs0 = t & 3, cg = cs0 ^ ((r >> 1) & 3);
  const u16* ga = A + (size_t)(bm + r) * HID + cg * 8;
  const u16* gb = Bt + (size_t)(bn + r) * HID + cg * 8;
  u16* la = As + w * 512;
  u16* lb = Bs + w * 512;
  const int wm = (w >> 1) * 64, wn = (w & 1) * 64;
  const u16* ra[4];
  const u16* rb[4];
  for (int mi = 0; mi < 4; mi++) {
    int row = wm + mi * 16 + (lane & 15);
    int cs = (lane >> 4) ^ ((row >> 1) & 3);
    ra[mi] = As + row * 32 + cs * 8;
  }
  for (int ni = 0; ni < 4; ni++) {
    int row = wn + ni * 16 + (lane & 15);
    int cs = (lane >> 4) ^ ((row >> 1) & 3);
    rb[ni] = Bs + row * 32 + cs * 8;
  }
  f32x4 acc[4][4] = {};
  for (int k0 = 0; k0 < HID; k0 += 32) {
    __syncthreads();
    cp16(ga, la);
    cp16(ga + 64 * HID, la + 2048);
    cp16(gb, lb);
    cp16(gb + 64 * HID, lb + 2048);
    ga += 32;
    gb += 32;
    __syncthreads();
    s16x8 af[4], bf[4];
    for (int mi = 0; mi < 4; mi++) af[mi] = *(const s16x8*)ra[mi];
    for (int ni = 0; ni < 4; ni++) bf[ni] = *(const s16x8*)rb[ni];
    for (int mi = 0; mi < 4; mi++)
      for (int ni = 0; ni < 4; ni++)
        acc[mi][ni] = __builtin_amdgcn_mfma_f32_16x16x32_bf16(af[mi], bf[ni], acc[mi][ni], 0, 0, 0);
  }
  // epilogue: C row=(lane>>4)*4+reg, col=lane&15 (m89-verified)
  for (int mi = 0; mi < 4; mi++)
    for (int ni = 0; ni < 4; ni++) {
      int ml = bm + wm + mi * 16 + ((lane >> 4) << 2);
      int nl = bn + wn + ni * 16 + (lane & 15);
      for (int rr = 0; rr < 4; rr++) {
        float v = acc[mi][ni][rr];
        if (QKV)
          Cb[(size_t)(ml + rr) * HID + nl] = f2bf(v * scale);
        else
          Cf[(size_t)(ml + rr) * HID + nl] = v;
      }
    }
}

// ---------------- interleaved RoPE on first 64 chans of each head ----------------
__global__ __launch_bounds__(256) void k_rope(u16* __restrict__ Q, u16* __restrict__ K,
                                              const int* __restrict__ pid) {
  int i = blockIdx.x * 256 + threadIdx.x;   // token*512 + head*32 + pair
  int m = i >> 9, rem = i & 511, h = rem >> 5, p = rem & 31;
  int pos = pid[m];
  double inv = pow(10000.0, -(double)p / 32.0);
  double ang = (double)pos * inv;
  float sv = (float)sin(ang), cv = (float)cos(ang);
  size_t idx = (size_t)m * HID + h * 256 + 2 * p;
  {
    unsigned int qp = *(const unsigned int*)(Q + idx);
    float a = bf2f((u16)qp), b = bf2f((u16)(qp >> 16));
    unsigned int o = (unsigned int)f2bf(a * cv - b * sv) |
                     ((unsigned int)f2bf(b * cv + a * sv) << 16);
    *(unsigned int*)(Q + idx) = o;
  }
  {
    unsigned int kp = *(const unsigned int*)(K + idx);
    float a = bf2f((u16)kp), b = bf2f((u16)(kp >> 16));
    unsigned int o = (unsigned int)f2bf(a * cv - b * sv) |
                     ((unsigned int)f2bf(b * cv + a * sv) << 16);
    *(unsigned int*)(K + idx) = o;
  }
}

// ---------------- flash attention (R2) ----------------
// BQ=64 (4 waves x 16 rows), BK=64, D=256. Grid (32 qt, 32 bh) = 1024 blocks.
// Per-wave state: oacc 64 + qf 32 VGPRs -> no spill at 256-cap.
__global__ __launch_bounds__(256, 2) void k_flash(const u16* __restrict__ Q,
                                                  const u16* __restrict__ Kg,
                                                  const u16* __restrict__ Vt,
                                                  const float* __restrict__ am,
                                                  u16* __restrict__ O) {
  __shared__ u16 smem[36864];        // 72 KB
  u16* sK = smem;                    // [64 kt][256 d]  swizzled, 32 chunks/row
  u16* sV = smem + 16384;            // [256 d][64 kt]  swizzled, 8 chunks/row
  u16* sP = smem + 32768;            // [64 q][64 kt]   swizzled, 8 chunks/row
  const int t = threadIdx.x, lane = t & 63, w = t >> 6;
  const int qt = gridDim.x - 1 - blockIdx.x;   // longest blocks first
  const int q0 = qt * 64;
  const int bh = blockIdx.y, b = bh >> 4, h = bh & 15;
  const size_t tokb = (size_t)b * SEQ;
  const int ch0 = h * 256;

  // Q tile 64x256 staged once through sK region, then kept in registers
  for (int j = 0; j < 8; j++) {
    int fc = j * 256 + t;
    int r = fc >> 5, cs = fc & 31, cg = cs ^ (r & 7);
    cp16(Q + (tokb + q0 + r) * (size_t)HID + ch0 + cg * 8, sK + j * 2048 + w * 512);
  }
  __syncthreads();
  s16x8 qf[8];
  {
    int rq = w * 16 + (lane & 15);
    for (int kf = 0; kf < 8; kf++) {
      int cs = ((lane >> 4) + 4 * kf) ^ (rq & 7);
      qf[kf] = *(const s16x8*)(sK + rq * 256 + cs * 8);
    }
  }
  f32x4 oacc[16] = {};
  float mrow[4], lrow[4];
  for (int rr = 0; rr < 4; rr++) { mrow[rr] = -1e30f; lrow[rr] = 0.f; }

  const int ntiles = qt + 1;
  for (int it = 0; it < ntiles; it++) {
    const int kt0 = it * 64;
    __syncthreads();   // prev-iter LDS reads done before restage
    for (int j = 0; j < 8; j++) {
      int fc = j * 256 + t;
      int r = fc >> 5, cs = fc & 31, cg = cs ^ (r & 7);
      cp16(Kg + (tokb + kt0 + r) * (size_t)HID + ch0 + cg * 8, sK + j * 2048 + w * 512);
    }
    for (int j = 0; j < 8; j++) {
      int fc = j * 256 + t;
      int rd = fc >> 3, cs = fc & 7, cg = cs ^ (rd & 7);
      cp16(Vt + ((size_t)bh * 256 + rd) * SEQ + kt0 + cg * 8, sV + j * 2048 + w * 512);
    }
    __syncthreads();
    // S = Q K^T  (M=16/wave, N=64, K=256)
    f32x4 sacc[4] = {};
    for (int kf = 0; kf < 8; kf++) {
      s16x8 bf[4];
      for (int ni = 0; ni < 4; ni++) {
        int rk = ni * 16 + (lane & 15);
        int cs = ((lane >> 4) + 4 * kf) ^ (rk & 7);
        bf[ni] = *(const s16x8*)(sK + rk * 256 + cs * 8);
      }
      for (int ni = 0; ni < 4; ni++)
        sacc[ni] = __builtin_amdgcn_mfma_f32_16x16x32_bf16(qf[kf], bf[ni], sacc[ni], 0, 0, 0);
    }
    // masks (pad + causal on diagonal tile only)
    float amv[4];
    for (int ni = 0; ni < 4; ni++) amv[ni] = am[b * SEQ + kt0 + ni * 16 + (lane & 15)];
    const bool tail = (kt0 + 64 > q0);
    {
      int rbase = q0 + w * 16 + ((lane >> 4) << 2);
      for (int ni = 0; ni < 4; ni++) {
        int colg = kt0 + ni * 16 + (lane & 15);
        bool dead = (amv[ni] <= 0.f);
        for (int rr = 0; rr < 4; rr++)
          if (dead || (tail && colg > rbase + rr)) sacc[ni][rr] = -1e30f;
      }
    }
    // online softmax (rows live in 16-lane groups; xor-shuffle 1,2,4,8)
    float alpha[4];
    for (int rr = 0; rr < 4; rr++) {
      float v = fmaxf(fmaxf(sacc[0][rr], sacc[1][rr]),
                      fmaxf(sacc[2][rr], sacc[3][rr]));
      v = fmaxf(v, __shfl_xor(v, 1));
      v = fmaxf(v, __shfl_xor(v, 2));
      v = fmaxf(v, __shfl_xor(v, 4));
      v = fmaxf(v, __shfl_xor(v, 8));
      float mnew = fmaxf(mrow[rr], v);
      alpha[rr] = __expf(mrow[rr] - mnew);
      mrow[rr] = mnew;
    }
    for (int ni = 0; ni < 4; ni++)
      for (int rr = 0; rr < 4; rr++)
        sacc[ni][rr] = __expf(sacc[ni][rr] - mrow[rr]);
    for (int rr = 0; rr < 4; rr++) {
      float sm = sacc[0][rr] + sacc[1][rr] + sacc[2][rr] + sacc[3][rr];
      sm += __shfl_xor(sm, 1);
      sm += __shfl_xor(sm, 2);
      sm += __shfl_xor(sm, 4);
      sm += __shfl_xor(sm, 8);
      lrow[rr] = lrow[rr] * alpha[rr] + sm;
    }
    for (int nd = 0; nd < 16; nd++)
      for (int rr = 0; rr < 4; rr++) oacc[nd][rr] *= alpha[rr];
    // P -> LDS (C-layout -> A-layout, wave-private rows; no barrier needed)
    for (int ni = 0; ni < 4; ni++) {
      int ktl = ni * 16 + (lane & 15);
      for (int rr = 0; rr < 4; rr++) {
        int pq = w * 16 + ((lane >> 4) << 2) + rr;
        int cs = (ktl >> 3) ^ (pq & 7);
        sP[pq * 64 + cs * 8 + (ktl & 7)] = f2bf(sacc[ni][rr]);
      }
    }
    // O += P V   (N=256, K=64)
    for (int kf2 = 0; kf2 < 2; kf2++) {
      s16x8 pa;
      {
        int pq = w * 16 + (lane & 15);
        int cs = ((lane >> 4) + 4 * kf2) ^ (pq & 7);
        pa = *(const s16x8*)(sP + pq * 64 + cs * 8);
      }
      for (int nd = 0; nd < 16; nd++) {
        int rd = nd * 16 + (lane & 15);
        int cs = ((lane >> 4) + 4 * kf2) ^ (rd & 7);
        s16x8 vb = *(const s16x8*)(sV + rd * 64 + cs * 8);
        oacc[nd] = __builtin_amdgcn_mfma_f32_16x16x32_bf16(pa, vb, oacc[nd], 0, 0, 0);
      }
    }
  }
  // epilogue: O / l -> bf16
  {
    float rl[4];
    for (int rr = 0; rr < 4; rr++) rl[rr] = (lrow[rr] > 0.f) ? 1.f / lrow[rr] : 0.f;
    for (int nd = 0; nd < 16; nd++)
      for (int rr = 0; rr < 4; rr++) {
        size_t row = tokb + q0 + w * 16 + ((lane >> 4) << 2) + rr;
        O[row * HID + ch0 + nd * 16 + (lane & 15)] = f2bf(oacc[nd][rr] * rl[rr]);
      }
  }
}

extern "C" void kernel_launch(void* const* d_in, const int* in_sizes, int n_in,
                              void* d_out, int out_size, void* d_ws, size_t ws_size,
                              hipStream_t stream) {
  const float* hs = (const float*)d_in[0];
  const float* am = (const float*)d_in[1];
  const int* pid = (const int*)d_in[2];
  const float* Wq = (const float*)d_in[3];
  const float* Wk = (const float*)d_in[4];
  const float* Wv = (const float*)d_in[5];
  const float* Wo = (const float*)d_in[6];
  float* out = (float*)d_out;

  u16* wsp = (u16*)d_ws;
  u16* hsb = wsp;                 // slot 0 (later: attn_out)
  u16* WT = wsp + NMAT;           // slots 1..4: WqT WkT WvT WoT
  u16* Qb = wsp + 5 * NMAT;
  u16* Kb = wsp + 6 * NMAT;
  u16* Vb = wsp + 7 * NMAT;
  u16* Vt = wsp + 1 * NMAT;       // reuse WqT after QKV GEMM
  u16* attn = hsb;                // reuse hs_bf16 after QKV GEMM

  k_cvt<<<8192, 256, 0, stream>>>(hs, hsb);
  k_wtrans<<<dim3(64, 64, 4), 256, 0, stream>>>(Wq, Wk, Wv, Wo, WT);
  k_gemm<true><<<dim3(32, 32, 3), 256, 0, stream>>>(hsb, WT, Qb, nullptr);
  k_rope<<<8192, 256, 0, stream>>>(Qb, Kb, pid);
  k_vtrans<<<dim3(32, 4, 32), 256, 0, stream>>>(Vb, Vt);
  k_flash<<<dim3(32, 32), 256, 0, stream>>>(Qb, Kb, Vt, am, attn);
  k_gemm<false><<<dim3(32, 32, 1), 256, 0, stream>>>(attn, WT + 3 * NMAT, nullptr, out);
}